// Round 3
// baseline (555.673 us; speedup 1.0000x reference)
//
#include <hip/hip_runtime.h>

#define SEQ 4096
#define DMODEL 1024
#define DSTATE 64
#define DINNER 2048
#define MROWS 8192            // BATCH*SEQ
#define NCAT 1152             // 1024 (dt) + 64 (xp) + 64 pad
#define NCHUNK 64             // scan chunks
#define LCHUNK 64             // steps per chunk

typedef __attribute__((ext_vector_type(8))) __bf16 bf16x8;
typedef __attribute__((ext_vector_type(8))) short short8;
typedef __attribute__((ext_vector_type(4))) float floatx4;

__device__ inline float bf2f(short s) {
  union { unsigned u; float f; } c;
  c.u = ((unsigned)(unsigned short)s) << 16;
  return c.f;
}
__device__ inline short f2bf(float f) {
  union { float f; unsigned u; } c; c.f = f;
  unsigned r = 0x7fffu + ((c.u >> 16) & 1u);
  return (short)((c.u + r) >> 16);
}
__device__ inline float silu_f(float v) {
  // v * sigmoid(v) with hw rcp (1-ulp-ish approx, fine for bf16 outputs)
  return v * __builtin_amdgcn_rcpf(1.f + __expf(-v));
}
__device__ inline float softplus_f(float v) {
  return fmaxf(v, 0.f) + log1pf(__expf(-fabsf(v)));
}
// async global->LDS, 16B per lane. LDS dest = wave-uniform base + lane*16.
__device__ inline void gld_lds16(const void* g, void* l) {
  __builtin_amdgcn_global_load_lds(
      (__attribute__((address_space(1))) void*)g,
      (__attribute__((address_space(3))) void*)l, 16, 0, 0);
}

// ---------------- fused pre-pass: x->bf16 + 4 weight transposes -------------
// segmented grid: [0,8192) cvt_x | [8192,12288) W_in^T | [12288,14336) W_dt^T
//                 [14336,14464) W_xp^T | [14464,16512) W_out^T
#define PRE_SEG0 8192
#define PRE_SEG1 (PRE_SEG0 + 4096)
#define PRE_SEG2 (PRE_SEG1 + 2048)
#define PRE_SEG3 (PRE_SEG2 + 128)
#define PRE_SEG4 (PRE_SEG3 + 2048)

__device__ void tile_transpose(const float* __restrict__ in, short* __restrict__ out,
                               int R, int C, int bx, int by, float (*tile)[33]) {
  const int tx = threadIdx.x & 31, ty = threadIdx.x >> 5;   // 32 x 8
  const int cb = bx * 32, rb = by * 32;
#pragma unroll
  for (int i = 0; i < 32; i += 8) {
    int r = rb + ty + i, c = cb + tx;
    tile[ty + i][tx] = (r < R && c < C) ? in[(size_t)r * C + c] : 0.f;
  }
  __syncthreads();
#pragma unroll
  for (int i = 0; i < 32; i += 8) {
    int orow = cb + ty + i, oc = rb + tx;   // out[c][r] = in[r][c]
    if (orow < C && oc < R) out[(size_t)orow * R + oc] = f2bf(tile[tx][ty + i]);
  }
}

__global__ void prepass_kernel(const float* __restrict__ x, short* __restrict__ x_bf,
                               const float* __restrict__ W_in, short* __restrict__ Wt_in,
                               const float* __restrict__ W_dt, const float* __restrict__ W_xp,
                               short* __restrict__ Bcat,
                               const float* __restrict__ W_out, short* __restrict__ Wt_out) {
  __shared__ float tile[32][33];
  const int blk = blockIdx.x;
  if (blk < PRE_SEG0) {
    int i = blk * 256 + threadIdx.x;           // 2M float4
    float4 v = ((const float4*)x)[i];
    short4 o;
    o.x = f2bf(v.x); o.y = f2bf(v.y); o.z = f2bf(v.z); o.w = f2bf(v.w);
    ((short4*)x_bf)[i] = o;
  } else if (blk < PRE_SEG1) {
    int t = blk - PRE_SEG0;
    tile_transpose(W_in, Wt_in, 1024, 4096, t & 127, t >> 7, tile);
  } else if (blk < PRE_SEG2) {
    int t = blk - PRE_SEG1;
    tile_transpose(W_dt, Bcat, 2048, 1024, t & 31, t >> 5, tile);
  } else if (blk < PRE_SEG3) {
    int t = blk - PRE_SEG2;
    tile_transpose(W_xp, Bcat + (size_t)1024 * DINNER, 2048, 64, t & 1, t >> 1, tile);
  } else {
    int t = blk - PRE_SEG3;
    tile_transpose(W_out, Wt_out, 2048, 1024, t & 31, t >> 5, tile);
  }
}

// ---------------- m97-style bf16 GEMM, C = A[M,K] * Bt[N,K]^T ----------------
// LDS layout (both sA and sB): granule (row r, 16B chunk c of the 32-short row)
// lives at slot (r>>4)*64 + c*16 + (r&15). Fragment reads are then linear in
// lane index -> conflict-free ds_read_b128 (was 8-way, 8.4M conflict cycles).
// MODE 0: in_proj epilogue -> xi=silu(col<2048), g=silu(col>=2048), both bf16
// MODE 1: dt/xp epilogue   -> col<1024: softplus+rowsum->md_sum (atomic)
//                             1024<=col<1088: bx fp32;  col>=1088: pad, drop
// MODE 2: out_proj epilogue-> out = v + b_out[col] + x[r,col]*D[col]  (fp32)
template <int MODE>
__global__ __launch_bounds__(256) void gemm_bt(
    const short* __restrict__ A, const short* __restrict__ Bt,
    const float* __restrict__ bias, const float* __restrict__ bias2,
    void* __restrict__ out0, void* __restrict__ out1,
    const float* __restrict__ xres, const float* __restrict__ Dvec,
    float* __restrict__ md_sum, int M, int N, int K)
{
  __shared__ __attribute__((aligned(16))) short sA[128 * 32];
  __shared__ __attribute__((aligned(16))) short sB[128 * 32];
  __shared__ float rowpart[128][2];

  const int tid = threadIdx.x;
  const int lane = tid & 63;
  const int w = tid >> 6;          // wave 0..3
  const int wr = w >> 1, wc = w & 1;
  const int m = lane & 15, quad = lane >> 4;
  const int bM = blockIdx.y * 128, bN = blockIdx.x * 128;

  floatx4 acc[4][4] = {};

  // staging lane->global mapping for panel-major LDS layout:
  // wave w stages panels 2w (slots w*128+lane) and 2w+1 (slots w*128+64+lane).
  // slot s: row = (s>>6)*16 + (s&15), chunk = (s>>4)&3.
  const int su = lane & 15, sc = (lane >> 4) & 3;
  const int r0 = 32 * w + su;            // panel 2w rows
  const int r1 = 32 * w + 16 + su;       // panel 2w+1 rows
  const short* A0 = A + (size_t)(bM + r0) * K + sc * 8;
  const short* A1 = A + (size_t)(bM + r1) * K + sc * 8;
  const short* B0 = Bt + (size_t)(bN + r0) * K + sc * 8;
  const short* B1 = Bt + (size_t)(bN + r1) * K + sc * 8;
  short* dA0 = sA + w * 1024;            // 1024 shorts = 128 granules/wave pair
  short* dA1 = sA + w * 1024 + 512;
  short* dB0 = sB + w * 1024;
  short* dB1 = sB + w * 1024 + 512;

  for (int k0 = 0; k0 < K; k0 += 32) {
    __syncthreads();
    gld_lds16(A0 + k0, dA0);
    gld_lds16(A1 + k0, dA1);
    gld_lds16(B0 + k0, dB0);
    gld_lds16(B1 + k0, dB1);
    __syncthreads();   // drains vmcnt incl. global_load_lds
    bf16x8 af[4], bf[4];
    // frag for (tile rt, row m, k-chunk quad): slot (wr*4+rt)*64 + quad*16 + m
#pragma unroll
    for (int rt = 0; rt < 4; ++rt)
      af[rt] = *(const bf16x8*)(sA + (((wr * 4 + rt) * 64 + quad * 16 + m) << 3));
#pragma unroll
    for (int ct = 0; ct < 4; ++ct)
      bf[ct] = *(const bf16x8*)(sB + (((wc * 4 + ct) * 64 + quad * 16 + m) << 3));
#pragma unroll
    for (int rt = 0; rt < 4; ++rt)
#pragma unroll
      for (int ct = 0; ct < 4; ++ct)
        acc[rt][ct] = __builtin_amdgcn_mfma_f32_16x16x32_bf16(af[rt], bf[ct], acc[rt][ct], 0, 0, 0);
  }

  const int rowbase = bM + wr * 64;
  const int colbase = bN + wc * 64;

  if (MODE == 0) {
    // whole block is one side of the 2048 split (bN multiple of 128)
    short* dst = (bN < DINNER) ? (short*)out0 : (short*)out1;
    const int cb = (bN < DINNER) ? colbase : colbase - DINNER;
#pragma unroll
    for (int rt = 0; rt < 4; ++rt)
#pragma unroll
      for (int ct = 0; ct < 4; ++ct) {
        const int col = colbase + ct * 16 + m;
#pragma unroll
        for (int reg = 0; reg < 4; ++reg) {
          const int r = rowbase + rt * 16 + quad * 4 + reg;
          float val = acc[rt][ct][reg] + bias[col];
          dst[(size_t)r * DINNER + cb + ct * 16 + m] = f2bf(silu_f(val));
        }
      }
  } else if (MODE == 1) {
    if (bN < 1024) {           // dt columns: softplus + row-sum
      float rsum[4][4];
#pragma unroll
      for (int rt = 0; rt < 4; ++rt)
#pragma unroll
        for (int reg = 0; reg < 4; ++reg) rsum[rt][reg] = 0.f;
#pragma unroll
      for (int rt = 0; rt < 4; ++rt)
#pragma unroll
        for (int ct = 0; ct < 4; ++ct) {
          const int col = colbase + ct * 16 + m;
#pragma unroll
          for (int reg = 0; reg < 4; ++reg)
            rsum[rt][reg] += softplus_f(acc[rt][ct][reg] + bias[col]);
        }
#pragma unroll
      for (int rt = 0; rt < 4; ++rt)
#pragma unroll
        for (int reg = 0; reg < 4; ++reg) {
          float v = rsum[rt][reg];
          v += __shfl_xor(v, 1); v += __shfl_xor(v, 2);
          v += __shfl_xor(v, 4); v += __shfl_xor(v, 8);
          if (m == 0) rowpart[wr * 64 + rt * 16 + quad * 4 + reg][wc] = v;
        }
      __syncthreads();
      if (tid < 128)
        atomicAdd(&md_sum[bM + tid], rowpart[tid][0] + rowpart[tid][1]);
    } else if (wc == 0) {      // cols 1024..1087 -> bx;  wc==1 (pad) dropped
      float* bx = (float*)out0;
#pragma unroll
      for (int rt = 0; rt < 4; ++rt)
#pragma unroll
        for (int ct = 0; ct < 4; ++ct) {
          const int cr = ct * 16 + m;   // 0..63 relative state index
#pragma unroll
          for (int reg = 0; reg < 4; ++reg) {
            const int r = rowbase + rt * 16 + quad * 4 + reg;
            bx[(size_t)r * DSTATE + cr] = acc[rt][ct][reg] + bias2[cr];
          }
        }
    }
  } else {
    float* out = (float*)out0;
#pragma unroll
    for (int rt = 0; rt < 4; ++rt)
#pragma unroll
      for (int ct = 0; ct < 4; ++ct) {
        const int col = colbase + ct * 16 + m;
#pragma unroll
        for (int reg = 0; reg < 4; ++reg) {
          const int r = rowbase + rt * 16 + quad * 4 + reg;
          out[(size_t)r * DMODEL + col] =
              acc[rt][ct][reg] + bias[col] + xres[(size_t)r * DMODEL + col] * Dvec[col];
        }
      }
  }
}

// ---------------- chunked selective scan (3 phases) --------------------------
__global__ void scan_phase1(const float* __restrict__ md_sum, const float* __restrict__ A_log,
                            const float* __restrict__ bx, float* __restrict__ a_buf,
                            float* __restrict__ chunk_prod, float* __restrict__ chunk_end) {
  const int n = threadIdx.x;                // 0..63 (state dim)
  const int c = blockIdx.x & (NCHUNK - 1);  // chunk
  const int b = blockIdx.x >> 6;            // batch
  const float An = -__expf(A_log[n]);
  float prod = 1.f, st = 0.f;
  const int t0 = c * LCHUNK;
  for (int i = 0; i < LCHUNK; ++i) {
    const int t = t0 + i;
    const float md = md_sum[b * SEQ + t] * (1.f / DMODEL);
    const float a = __expf(An * md);
    const size_t idx = ((size_t)(b * SEQ + t)) * DSTATE + n;
    st = a * st + bx[idx];
    prod *= a;
    a_buf[idx] = a;
  }
  chunk_prod[(b * NCHUNK + c) * DSTATE + n] = prod;
  chunk_end [(b * NCHUNK + c) * DSTATE + n] = st;
}

__global__ void scan_phase2(const float* __restrict__ chunk_prod,
                            const float* __restrict__ chunk_end,
                            float* __restrict__ chunk_init) {
  const int i = threadIdx.x;   // 0..127 = b*64 + n
  const int b = i >> 6, n = i & 63;
  float st = 0.f;
  for (int c = 0; c < NCHUNK; ++c) {
    const size_t idx = ((size_t)(b * NCHUNK + c)) * DSTATE + n;
    chunk_init[idx] = st;
    st = chunk_prod[idx] * st + chunk_end[idx];
  }
}

__global__ void scan_phase3(const float* __restrict__ a_buf, const float* __restrict__ bx,
                            const float* __restrict__ chunk_init, float* __restrict__ s_sum) {
  const int n = threadIdx.x;
  const int c = blockIdx.x & (NCHUNK - 1);
  const int b = blockIdx.x >> 6;
  float st = chunk_init[((size_t)(b * NCHUNK + c)) * DSTATE + n];
  const int t0 = c * LCHUNK;
  for (int i = 0; i < LCHUNK; ++i) {
    const int t = t0 + i;
    const size_t idx = ((size_t)(b * SEQ + t)) * DSTATE + n;
    st = a_buf[idx] * st + bx[idx];
    float v = st;
    v += __shfl_xor(v, 32); v += __shfl_xor(v, 16); v += __shfl_xor(v, 8);
    v += __shfl_xor(v, 4);  v += __shfl_xor(v, 2);  v += __shfl_xor(v, 1);
    if (n == 0) s_sum[b * SEQ + t] = v;
  }
}

// ---------------- y = s_sum * xi * g  (bf16 out) ------------------------------
__global__ void ymul_kernel(const short* __restrict__ xi, const short* __restrict__ g,
                            const float* __restrict__ s_sum, short* __restrict__ y) {
  const int row = blockIdx.x;
  const size_t base = (size_t)row * DINNER + threadIdx.x * 8;
  const float s = s_sum[row];
  short8 xv = *(const short8*)(xi + base);
  short8 gv = *(const short8*)(g + base);
  short8 yv;
#pragma unroll
  for (int k = 0; k < 8; ++k) yv[k] = f2bf(s * bf2f(xv[k]) * bf2f(gv[k]));
  *(short8*)(y + base) = yv;
}

// ---------------- launch ------------------------------------------------------
extern "C" void kernel_launch(void* const* d_in, const int* in_sizes, int n_in,
                              void* d_out, int out_size, void* d_ws, size_t ws_size,
                              hipStream_t stream) {
  const float* x     = (const float*)d_in[0];
  const float* W_in  = (const float*)d_in[1];
  const float* b_in  = (const float*)d_in[2];
  const float* W_xp  = (const float*)d_in[3];
  const float* b_xp  = (const float*)d_in[4];
  const float* W_dt  = (const float*)d_in[5];
  const float* b_dt  = (const float*)d_in[6];
  const float* W_out = (const float*)d_in[7];
  const float* b_out = (const float*)d_in[8];
  const float* A_log = (const float*)d_in[9];
  const float* Dv    = (const float*)d_in[10];

  char* ws = (char*)d_ws;
  size_t off = 0;
  auto alloc = [&](size_t bytes) -> void* {
    void* p = (void*)(ws + off);
    off += (bytes + 255) & ~(size_t)255;
    return p;
  };
  short* x_bf    = (short*)alloc((size_t)MROWS * DMODEL * 2);
  short* Wt_in   = (short*)alloc((size_t)4096 * 1024 * 2);
  short* Bcat    = (short*)alloc((size_t)NCAT * DINNER * 2);
  short* Wt_out  = (short*)alloc((size_t)1024 * 2048 * 2);
  short* xi      = (short*)alloc((size_t)MROWS * DINNER * 2);
  short* gbuf    = (short*)alloc((size_t)MROWS * DINNER * 2);
  short* ybuf    = (short*)alloc((size_t)MROWS * DINNER * 2);
  float* md_sum  = (float*)alloc((size_t)MROWS * 4);
  float* bx      = (float*)alloc((size_t)MROWS * DSTATE * 4);
  float* a_buf   = (float*)alloc((size_t)MROWS * DSTATE * 4);
  float* cprod   = (float*)alloc((size_t)2 * NCHUNK * DSTATE * 4);
  float* cend    = (float*)alloc((size_t)2 * NCHUNK * DSTATE * 4);
  float* cinit   = (float*)alloc((size_t)2 * NCHUNK * DSTATE * 4);
  float* s_sum   = (float*)alloc((size_t)MROWS * 4);

  hipMemsetAsync(md_sum, 0, (size_t)MROWS * 4, stream);
  // fused pre-pass: x->bf16 + all 4 weight transposes (one dispatch)
  prepass_kernel<<<PRE_SEG4, 256, 0, stream>>>(x, x_bf, W_in, Wt_in, W_dt, W_xp, Bcat, W_out, Wt_out);

  // GEMM1: in_proj + silu split
  gemm_bt<0><<<dim3(4096 / 128, MROWS / 128), 256, 0, stream>>>(
      x_bf, Wt_in, b_in, nullptr, xi, gbuf, nullptr, nullptr, nullptr, MROWS, 4096, 1024);
  // GEMM2: dt (softplus rowsum) + xp (bx)
  gemm_bt<1><<<dim3(NCAT / 128, MROWS / 128), 256, 0, stream>>>(
      xi, Bcat, b_dt, b_xp, bx, nullptr, nullptr, nullptr, md_sum, MROWS, NCAT, 2048);
  // selective scan
  scan_phase1<<<2 * NCHUNK, DSTATE, 0, stream>>>(md_sum, A_log, bx, a_buf, cprod, cend);
  scan_phase2<<<1, 128, 0, stream>>>(cprod, cend, cinit);
  scan_phase3<<<2 * NCHUNK, DSTATE, 0, stream>>>(a_buf, bx, cinit, s_sum);
  // y = s_sum * xi * g
  ymul_kernel<<<MROWS, 256, 0, stream>>>(xi, gbuf, s_sum, ybuf);
  // GEMM4: out_proj + b_out + x*D
  gemm_bt<2><<<dim3(1024 / 128, MROWS / 128), 256, 0, stream>>>(
      ybuf, Wt_out, b_out, nullptr, d_out, nullptr, x, Dv, nullptr, MROWS, 1024, 2048);
}

// Round 4
// 472.411 us; speedup vs baseline: 1.1762x; 1.1762x over previous
//
#include <hip/hip_runtime.h>

#define SEQ 4096
#define DMODEL 1024
#define DSTATE 64
#define DINNER 2048
#define MROWS 8192            // BATCH*SEQ
#define NCAT 1152             // 1024 (dt) + 64 (xp) + 64 pad
#define NCHUNK 64             // scan chunks
#define LCHUNK 64             // steps per chunk

typedef __attribute__((ext_vector_type(8))) __bf16 bf16x8;
typedef __attribute__((ext_vector_type(8))) short short8;
typedef __attribute__((ext_vector_type(4))) float floatx4;

__device__ inline float bf2f(short s) {
  union { unsigned u; float f; } c;
  c.u = ((unsigned)(unsigned short)s) << 16;
  return c.f;
}
__device__ inline short f2bf(float f) {
  union { float f; unsigned u; } c; c.f = f;
  unsigned r = 0x7fffu + ((c.u >> 16) & 1u);
  return (short)((c.u + r) >> 16);
}
__device__ inline float silu_f(float v) {
  return v * __builtin_amdgcn_rcpf(1.f + __expf(-v));
}
__device__ inline float softplus_f(float v) {
  return fmaxf(v, 0.f) + log1pf(__expf(-fabsf(v)));
}
// async global->LDS, 16B per lane. LDS dest = wave-uniform base + lane*16.
__device__ inline void gld_lds16(const void* g, void* l) {
  __builtin_amdgcn_global_load_lds(
      (__attribute__((address_space(1))) void*)g,
      (__attribute__((address_space(3))) void*)l, 16, 0, 0);
}

// panel-staged bf16 layout: panel = 16 rows, stored contiguously (K*32 bytes),
// inside: [k-chunk of 8][row-in-panel 16][8 elems].  element (r,k):
__device__ inline size_t permOff(int r, int k, int K) {
  return (((size_t)(r >> 4) * (K >> 3) + (k >> 3)) << 7) + ((r & 15) << 3) + (k & 7);
}

// ---------------- fused pre-pass ---------------------------------------------
// [0,4096) cvt_x (permuted K=1024) | [4096,8192) W_in^T | [8192,10240) W_dt^T
// [10240,10368) W_xp^T | [10368,12416) W_out^T
#define PP0 4096
#define PP1 (PP0 + 4096)
#define PP2 (PP1 + 2048)
#define PP3 (PP2 + 128)
#define PP4 (PP3 + 2048)

__device__ void tile_transpose_perm(const float* __restrict__ in, short* __restrict__ out,
                                    int R, int C, int bx, int by, float (*tile)[33]) {
  const int tx = threadIdx.x & 31, ty = threadIdx.x >> 5;   // 32 x 8
  const int cb = bx * 32, rb = by * 32;
#pragma unroll
  for (int i = 0; i < 32; i += 8) {
    int r = rb + ty + i, c = cb + tx;
    tile[ty + i][tx] = (r < R && c < C) ? in[(size_t)r * C + c] : 0.f;
  }
  __syncthreads();
#pragma unroll
  for (int i = 0; i < 32; i += 8) {
    int orow = cb + ty + i, oc = rb + tx;   // out(row=orow, k=oc) = in[oc][orow]
    if (orow < C && oc < R) out[permOff(orow, oc, R)] = f2bf(tile[tx][ty + i]);
  }
}

__global__ void prepass_kernel(const float* __restrict__ x, short* __restrict__ x_bf,
                               const float* __restrict__ W_in, short* __restrict__ Wt_in,
                               const float* __restrict__ W_dt, const float* __restrict__ W_xp,
                               short* __restrict__ Bcat,
                               const float* __restrict__ W_out, short* __restrict__ Wt_out) {
  __shared__ float tile[32][33];
  const int blk = blockIdx.x;
  if (blk < PP0) {
    // x (fp32 row-major [8192,1024]) -> x_bf panel-staged, one 16B group/thread
    int o = blk * 256 + threadIdx.x;            // [0, 1M)
    int m = o & 15, rest = o >> 4;
    int c = rest & 127, p = rest >> 7;          // K/8 = 128 chunks
    const float* src = x + ((size_t)(p * 16 + m)) * 1024 + c * 8;
    float4 v0 = ((const float4*)src)[0];
    float4 v1 = ((const float4*)src)[1];
    short8 ov;
    ov[0] = f2bf(v0.x); ov[1] = f2bf(v0.y); ov[2] = f2bf(v0.z); ov[3] = f2bf(v0.w);
    ov[4] = f2bf(v1.x); ov[5] = f2bf(v1.y); ov[6] = f2bf(v1.z); ov[7] = f2bf(v1.w);
    ((short8*)x_bf)[o] = ov;
  } else if (blk < PP1) {
    int t = blk - PP0;
    tile_transpose_perm(W_in, Wt_in, 1024, 4096, t & 127, t >> 7, tile);
  } else if (blk < PP2) {
    int t = blk - PP1;
    tile_transpose_perm(W_dt, Bcat, 2048, 1024, t & 31, t >> 5, tile);
  } else if (blk < PP3) {
    int t = blk - PP2;
    tile_transpose_perm(W_xp, Bcat + (size_t)1024 * DINNER, 2048, 64, t & 1, t >> 1, tile);
  } else {
    int t = blk - PP3;
    tile_transpose_perm(W_out, Wt_out, 2048, 1024, t & 31, t >> 5, tile);
  }
}

// ---------------- bf16 GEMM on panel-staged operands -------------------------
// A: [M,K] panel-staged, Bt: [N,K] panel-staged.  Staging: each wave async-copies
// panels w and w+4 of A and B (1KB contiguous per instruction, lane-linear).
// LDS image == round-3 layout -> conflict-free ds_read_b128 frag reads.
// MODE 0: xi=silu (bN<2048) / g=silu (bN>=2048), PANEL-STAGED bf16 out (K=2048)
// MODE 1: bN<1024: softplus+rowsum->md_sum; bN==1024,wc==0: bx fp32; rest drop
// MODE 2: out = v + b_out[col] + x[r,col]*D[col]  (fp32 row-major)
template <int MODE>
__global__ __launch_bounds__(256) void gemm_bt(
    const short* __restrict__ A, const short* __restrict__ Bt,
    const float* __restrict__ bias, const float* __restrict__ bias2,
    void* __restrict__ out0, void* __restrict__ out1,
    const float* __restrict__ xres, const float* __restrict__ Dvec,
    float* __restrict__ md_sum, int M, int N, int K)
{
  __shared__ __attribute__((aligned(16))) short sA[128 * 32];
  __shared__ __attribute__((aligned(16))) short sB[128 * 32];
  __shared__ float rowpart[128][2];

  const int tid = threadIdx.x;
  const int lane = tid & 63;
  const int w = tid >> 6;          // wave 0..3
  const int wr = w >> 1, wc = w & 1;
  const int m = lane & 15, quad = lane >> 4;
  const int bM = blockIdx.y * 128, bN = blockIdx.x * 128;

  floatx4 acc[4][4] = {};

  const size_t PS = (size_t)K * 16;               // panel stride (shorts)
  const short* Apan0 = A  + ((size_t)(bM >> 4) + w) * PS + lane * 8;
  const short* Apan1 = Apan0 + 4 * PS;
  const short* Bpan0 = Bt + ((size_t)(bN >> 4) + w) * PS + lane * 8;
  const short* Bpan1 = Bpan0 + 4 * PS;
  short* dA0 = sA + w * 512;
  short* dA1 = sA + (w + 4) * 512;
  short* dB0 = sB + w * 512;
  short* dB1 = sB + (w + 4) * 512;

  for (int k0 = 0; k0 < K; k0 += 32) {
    __syncthreads();
    const size_t ko = (size_t)k0 * 16;            // 32 k -> 512 shorts per panel
    gld_lds16(Apan0 + ko, dA0);
    gld_lds16(Apan1 + ko, dA1);
    gld_lds16(Bpan0 + ko, dB0);
    gld_lds16(Bpan1 + ko, dB1);
    __syncthreads();   // drains vmcnt incl. global_load_lds
    bf16x8 af[4], bf[4];
#pragma unroll
    for (int rt = 0; rt < 4; ++rt)
      af[rt] = *(const bf16x8*)(sA + (((wr * 4 + rt) * 64 + quad * 16 + m) << 3));
#pragma unroll
    for (int ct = 0; ct < 4; ++ct)
      bf[ct] = *(const bf16x8*)(sB + (((wc * 4 + ct) * 64 + quad * 16 + m) << 3));
#pragma unroll
    for (int rt = 0; rt < 4; ++rt)
#pragma unroll
      for (int ct = 0; ct < 4; ++ct)
        acc[rt][ct] = __builtin_amdgcn_mfma_f32_16x16x32_bf16(af[rt], bf[ct], acc[rt][ct], 0, 0, 0);
  }

  const int rowbase = bM + wr * 64;
  const int colbase = bN + wc * 64;

  if (MODE == 0) {
    short* dst = (bN < DINNER) ? (short*)out0 : (short*)out1;
    const int cb = (bN < DINNER) ? colbase : colbase - DINNER;
#pragma unroll
    for (int rt = 0; rt < 4; ++rt) {
      const size_t rowPan = ((size_t)((rowbase >> 4) + rt)) << 8;   // *256 chunks
#pragma unroll
      for (int ct = 0; ct < 4; ++ct) {
        const int colA = colbase + ct * 16 + m;      // for bias
        const int colP = cb + ct * 16 + m;           // within 2048-wide target
        const size_t base = ((rowPan + (colP >> 3)) << 7) + (colP & 7) + ((size_t)quad * 32);
#pragma unroll
        for (int reg = 0; reg < 4; ++reg) {
          float val = acc[rt][ct][reg] + bias[colA];
          dst[base + reg * 8] = f2bf(silu_f(val));   // (r&15)=quad*4+reg -> +8 shorts/reg
        }
      }
    }
  } else if (MODE == 1) {
    if (bN < 1024) {           // dt columns: softplus + row-sum
      float rsum[4][4];
#pragma unroll
      for (int rt = 0; rt < 4; ++rt)
#pragma unroll
        for (int reg = 0; reg < 4; ++reg) rsum[rt][reg] = 0.f;
#pragma unroll
      for (int rt = 0; rt < 4; ++rt)
#pragma unroll
        for (int ct = 0; ct < 4; ++ct) {
          const int col = colbase + ct * 16 + m;
#pragma unroll
          for (int reg = 0; reg < 4; ++reg)
            rsum[rt][reg] += softplus_f(acc[rt][ct][reg] + bias[col]);
        }
#pragma unroll
      for (int rt = 0; rt < 4; ++rt)
#pragma unroll
        for (int reg = 0; reg < 4; ++reg) {
          float v = rsum[rt][reg];
          v += __shfl_xor(v, 1); v += __shfl_xor(v, 2);
          v += __shfl_xor(v, 4); v += __shfl_xor(v, 8);
          if (m == 0) rowpart[wr * 64 + rt * 16 + quad * 4 + reg][wc] = v;
        }
      __syncthreads();
      if (tid < 128)
        atomicAdd(&md_sum[bM + tid], rowpart[tid][0] + rowpart[tid][1]);
    } else if (wc == 0) {      // cols 1024..1087 -> bx;  cols>=1088 dropped
      float* bx = (float*)out0;
#pragma unroll
      for (int rt = 0; rt < 4; ++rt)
#pragma unroll
        for (int ct = 0; ct < 4; ++ct) {
          const int cr = ct * 16 + m;
#pragma unroll
          for (int reg = 0; reg < 4; ++reg) {
            const int r = rowbase + rt * 16 + quad * 4 + reg;
            bx[(size_t)r * DSTATE + cr] = acc[rt][ct][reg] + bias2[cr];
          }
        }
    }
  } else {
    float* out = (float*)out0;
#pragma unroll
    for (int rt = 0; rt < 4; ++rt)
#pragma unroll
      for (int ct = 0; ct < 4; ++ct) {
        const int col = colbase + ct * 16 + m;
#pragma unroll
        for (int reg = 0; reg < 4; ++reg) {
          const int r = rowbase + rt * 16 + quad * 4 + reg;
          out[(size_t)r * DMODEL + col] =
              acc[rt][ct][reg] + bias[col] + xres[(size_t)r * DMODEL + col] * Dvec[col];
        }
      }
  }
}

// ---------------- chunked selective scan (3 phases) --------------------------
__global__ void scan_phase1(const float* __restrict__ md_sum, const float* __restrict__ A_log,
                            const float* __restrict__ bx, float* __restrict__ a_buf,
                            float* __restrict__ chunk_prod, float* __restrict__ chunk_end) {
  const int n = threadIdx.x;                // 0..63 (state dim)
  const int c = blockIdx.x & (NCHUNK - 1);  // chunk
  const int b = blockIdx.x >> 6;            // batch
  const float An = -__expf(A_log[n]);
  float prod = 1.f, st = 0.f;
  const int t0 = c * LCHUNK;
  for (int i = 0; i < LCHUNK; ++i) {
    const int t = t0 + i;
    const float md = md_sum[b * SEQ + t] * (1.f / DMODEL);
    const float a = __expf(An * md);
    const size_t idx = ((size_t)(b * SEQ + t)) * DSTATE + n;
    st = a * st + bx[idx];
    prod *= a;
    a_buf[idx] = a;
  }
  chunk_prod[(b * NCHUNK + c) * DSTATE + n] = prod;
  chunk_end [(b * NCHUNK + c) * DSTATE + n] = st;
}

__global__ void scan_phase2(const float* __restrict__ chunk_prod,
                            const float* __restrict__ chunk_end,
                            float* __restrict__ chunk_init) {
  const int i = threadIdx.x;   // 0..127 = b*64 + n
  const int b = i >> 6, n = i & 63;
  float st = 0.f;
  for (int c = 0; c < NCHUNK; ++c) {
    const size_t idx = ((size_t)(b * NCHUNK + c)) * DSTATE + n;
    chunk_init[idx] = st;
    st = chunk_prod[idx] * st + chunk_end[idx];
  }
}

__global__ void scan_phase3(const float* __restrict__ a_buf, const float* __restrict__ bx,
                            const float* __restrict__ chunk_init, float* __restrict__ s_sum) {
  const int n = threadIdx.x;
  const int c = blockIdx.x & (NCHUNK - 1);
  const int b = blockIdx.x >> 6;
  float st = chunk_init[((size_t)(b * NCHUNK + c)) * DSTATE + n];
  const int t0 = c * LCHUNK;
  for (int i = 0; i < LCHUNK; ++i) {
    const int t = t0 + i;
    const size_t idx = ((size_t)(b * SEQ + t)) * DSTATE + n;
    st = a_buf[idx] * st + bx[idx];
    float v = st;
    v += __shfl_xor(v, 32); v += __shfl_xor(v, 16); v += __shfl_xor(v, 8);
    v += __shfl_xor(v, 4);  v += __shfl_xor(v, 2);  v += __shfl_xor(v, 1);
    if (n == 0) s_sum[b * SEQ + t] = v;
  }
}

// ---------------- y = s_sum * xi * g  (panel-staged in AND out, K=2048) ------
__global__ void ymul_kernel(const short* __restrict__ xi, const short* __restrict__ g,
                            const float* __restrict__ s_sum, short* __restrict__ y) {
  const int o = blockIdx.x * 256 + threadIdx.x;    // 16B group index, [0, 2M)
  const int row = ((o >> 12) << 4) | (o & 15);     // panel p = o>>12 (256 chunks)
  const size_t base = (size_t)o * 8;
  const float s = s_sum[row];
  short8 xv = *(const short8*)(xi + base);
  short8 gv = *(const short8*)(g + base);
  short8 yv;
#pragma unroll
  for (int k = 0; k < 8; ++k) yv[k] = f2bf(s * bf2f(xv[k]) * bf2f(gv[k]));
  *(short8*)(y + base) = yv;
}

// ---------------- launch ------------------------------------------------------
extern "C" void kernel_launch(void* const* d_in, const int* in_sizes, int n_in,
                              void* d_out, int out_size, void* d_ws, size_t ws_size,
                              hipStream_t stream) {
  const float* x     = (const float*)d_in[0];
  const float* W_in  = (const float*)d_in[1];
  const float* b_in  = (const float*)d_in[2];
  const float* W_xp  = (const float*)d_in[3];
  const float* b_xp  = (const float*)d_in[4];
  const float* W_dt  = (const float*)d_in[5];
  const float* b_dt  = (const float*)d_in[6];
  const float* W_out = (const float*)d_in[7];
  const float* b_out = (const float*)d_in[8];
  const float* A_log = (const float*)d_in[9];
  const float* Dv    = (const float*)d_in[10];

  char* ws = (char*)d_ws;
  size_t off = 0;
  auto alloc = [&](size_t bytes) -> void* {
    void* p = (void*)(ws + off);
    off += (bytes + 255) & ~(size_t)255;
    return p;
  };
  short* x_bf    = (short*)alloc((size_t)MROWS * DMODEL * 2);
  short* Wt_in   = (short*)alloc((size_t)4096 * 1024 * 2);
  short* Bcat    = (short*)alloc((size_t)NCAT * DINNER * 2);
  short* Wt_out  = (short*)alloc((size_t)1024 * 2048 * 2);
  short* xi      = (short*)alloc((size_t)MROWS * DINNER * 2);
  short* gbuf    = (short*)alloc((size_t)MROWS * DINNER * 2);
  short* ybuf    = (short*)alloc((size_t)MROWS * DINNER * 2);
  float* md_sum  = (float*)alloc((size_t)MROWS * 4);
  float* bx      = (float*)alloc((size_t)MROWS * DSTATE * 4);
  float* a_buf   = (float*)alloc((size_t)MROWS * DSTATE * 4);
  float* cprod   = (float*)alloc((size_t)2 * NCHUNK * DSTATE * 4);
  float* cend    = (float*)alloc((size_t)2 * NCHUNK * DSTATE * 4);
  float* cinit   = (float*)alloc((size_t)2 * NCHUNK * DSTATE * 4);
  float* s_sum   = (float*)alloc((size_t)MROWS * 4);

  hipMemsetAsync(md_sum, 0, (size_t)MROWS * 4, stream);
  // fused pre-pass: x->bf16 (panel-staged) + all 4 weight transposes (panel-staged)
  prepass_kernel<<<PP4, 256, 0, stream>>>(x, x_bf, W_in, Wt_in, W_dt, W_xp, Bcat, W_out, Wt_out);

  // GEMM1: in_proj + silu split (outputs panel-staged K=2048)
  gemm_bt<0><<<dim3(4096 / 128, MROWS / 128), 256, 0, stream>>>(
      x_bf, Wt_in, b_in, nullptr, xi, gbuf, nullptr, nullptr, nullptr, MROWS, 4096, 1024);
  // GEMM2: dt (softplus rowsum) + xp (bx)
  gemm_bt<1><<<dim3(NCAT / 128, MROWS / 128), 256, 0, stream>>>(
      xi, Bcat, b_dt, b_xp, bx, nullptr, nullptr, nullptr, md_sum, MROWS, NCAT, 2048);
  // selective scan
  scan_phase1<<<2 * NCHUNK, DSTATE, 0, stream>>>(md_sum, A_log, bx, a_buf, cprod, cend);
  scan_phase2<<<1, 128, 0, stream>>>(cprod, cend, cinit);
  scan_phase3<<<2 * NCHUNK, DSTATE, 0, stream>>>(a_buf, bx, cinit, s_sum);
  // y = s_sum * xi * g (panel-staged)
  ymul_kernel<<<MROWS * DINNER / 8 / 256, 256, 0, stream>>>(xi, gbuf, s_sum, ybuf);
  // GEMM4: out_proj + b_out + x*D
  gemm_bt<2><<<dim3(1024 / 128, MROWS / 128), 256, 0, stream>>>(
      ybuf, Wt_out, b_out, nullptr, d_out, nullptr, x, Dv, nullptr, MROWS, 1024, 2048);
}

// Round 5
// 435.922 us; speedup vs baseline: 1.2747x; 1.0837x over previous
//
#include <hip/hip_runtime.h>

#define SEQ 4096
#define DMODEL 1024
#define DSTATE 64
#define DINNER 2048
#define MROWS 8192            // BATCH*SEQ
#define NCAT 1152             // 1024 (dt) + 64 (xp) + 64 pad
#define NCHUNK 64             // scan chunks
#define LCHUNK 64             // steps per chunk

typedef __attribute__((ext_vector_type(8))) __bf16 bf16x8;
typedef __attribute__((ext_vector_type(8))) short short8;
typedef __attribute__((ext_vector_type(4))) float floatx4;

__device__ inline float bf2f(short s) {
  union { unsigned u; float f; } c;
  c.u = ((unsigned)(unsigned short)s) << 16;
  return c.f;
}
__device__ inline short f2bf(float f) {
  union { float f; unsigned u; } c; c.f = f;
  unsigned r = 0x7fffu + ((c.u >> 16) & 1u);
  return (short)((c.u + r) >> 16);
}
__device__ inline float silu_f(float v) {
  return v * __builtin_amdgcn_rcpf(1.f + __expf(-v));
}
__device__ inline float softplus_f(float v) {
  return fmaxf(v, 0.f) + log1pf(__expf(-fabsf(v)));
}
// async global->LDS, 16B per lane. LDS dest = wave-uniform base + lane*16.
__device__ inline void gld_lds16(const void* g, void* l) {
  __builtin_amdgcn_global_load_lds(
      (__attribute__((address_space(1))) void*)g,
      (__attribute__((address_space(3))) void*)l, 16, 0, 0);
}

// panel-staged bf16 layout: panel = 16 rows, stored contiguously (K*32 bytes),
// inside: [k-chunk of 8][row-in-panel 16][8 elems].  element (r,k):
__device__ inline size_t permOff(int r, int k, int K) {
  return (((size_t)(r >> 4) * (K >> 3) + (k >> 3)) << 7) + ((r & 15) << 3) + (k & 7);
}

// ---------------- fused pre-pass ---------------------------------------------
#define PP0 4096
#define PP1 (PP0 + 4096)
#define PP2 (PP1 + 2048)
#define PP3 (PP2 + 128)
#define PP4 (PP3 + 2048)

__device__ void tile_transpose_perm(const float* __restrict__ in, short* __restrict__ out,
                                    int R, int C, int bx, int by, float (*tile)[33]) {
  const int tx = threadIdx.x & 31, ty = threadIdx.x >> 5;   // 32 x 8
  const int cb = bx * 32, rb = by * 32;
#pragma unroll
  for (int i = 0; i < 32; i += 8) {
    int r = rb + ty + i, c = cb + tx;
    tile[ty + i][tx] = (r < R && c < C) ? in[(size_t)r * C + c] : 0.f;
  }
  __syncthreads();
#pragma unroll
  for (int i = 0; i < 32; i += 8) {
    int orow = cb + ty + i, oc = rb + tx;   // out(row=orow, k=oc) = in[oc][orow]
    if (orow < C && oc < R) out[permOff(orow, oc, R)] = f2bf(tile[tx][ty + i]);
  }
}

__global__ void prepass_kernel(const float* __restrict__ x, short* __restrict__ x_bf,
                               const float* __restrict__ W_in, short* __restrict__ Wt_in,
                               const float* __restrict__ W_dt, const float* __restrict__ W_xp,
                               short* __restrict__ Bcat,
                               const float* __restrict__ W_out, short* __restrict__ Wt_out) {
  __shared__ float tile[32][33];
  const int blk = blockIdx.x;
  if (blk < PP0) {
    int o = blk * 256 + threadIdx.x;            // [0, 1M) 16B groups
    int m = o & 15, rest = o >> 4;
    int c = rest & 127, p = rest >> 7;          // K/8 = 128 chunks
    const float* src = x + ((size_t)(p * 16 + m)) * 1024 + c * 8;
    float4 v0 = ((const float4*)src)[0];
    float4 v1 = ((const float4*)src)[1];
    short8 ov;
    ov[0] = f2bf(v0.x); ov[1] = f2bf(v0.y); ov[2] = f2bf(v0.z); ov[3] = f2bf(v0.w);
    ov[4] = f2bf(v1.x); ov[5] = f2bf(v1.y); ov[6] = f2bf(v1.z); ov[7] = f2bf(v1.w);
    ((short8*)x_bf)[o] = ov;
  } else if (blk < PP1) {
    int t = blk - PP0;
    tile_transpose_perm(W_in, Wt_in, 1024, 4096, t & 127, t >> 7, tile);
  } else if (blk < PP2) {
    int t = blk - PP1;
    tile_transpose_perm(W_dt, Bcat, 2048, 1024, t & 31, t >> 5, tile);
  } else if (blk < PP3) {
    int t = blk - PP2;
    tile_transpose_perm(W_xp, Bcat + (size_t)1024 * DINNER, 2048, 64, t & 1, t >> 1, tile);
  } else {
    int t = blk - PP3;
    tile_transpose_perm(W_out, Wt_out, 2048, 1024, t & 31, t >> 5, tile);
  }
}

// ---------------- bf16 GEMM on panel-staged operands -------------------------
// A: [M,K] panel-staged, Bt: [N,K] panel-staged. 1KB contiguous staging per
// global_load_lds; LDS image conflict-free for ds_read_b128 frag reads.
// MODE 0: full-K; xi=silu (bN<2048) / g=silu (bN>=2048), panel-staged bf16 out
// MODE 1: K-slice z (len KSL); writes RAW acc as bf16 partial, row-major
//         stride N, at out0 + z*M*N  (split-K partial; bias added in epilogue)
template <int MODE>
__global__ __launch_bounds__(256) void gemm_bt(
    const short* __restrict__ A, const short* __restrict__ Bt,
    const float* __restrict__ bias,
    void* __restrict__ out0, void* __restrict__ out1,
    int M, int N, int K, int KSL)
{
  __shared__ __attribute__((aligned(16))) short sA[128 * 32];
  __shared__ __attribute__((aligned(16))) short sB[128 * 32];

  const int tid = threadIdx.x;
  const int lane = tid & 63;
  const int w = tid >> 6;          // wave 0..3
  const int wr = w >> 1, wc = w & 1;
  const int m = lane & 15, quad = lane >> 4;
  const int bM = blockIdx.y * 128, bN = blockIdx.x * 128;

  floatx4 acc[4][4] = {};

  const size_t PS = (size_t)K * 16;               // panel stride (shorts)
  const short* Apan0 = A  + ((size_t)(bM >> 4) + w) * PS + lane * 8;
  const short* Apan1 = Apan0 + 4 * PS;
  const short* Bpan0 = Bt + ((size_t)(bN >> 4) + w) * PS + lane * 8;
  const short* Bpan1 = Bpan0 + 4 * PS;
  short* dA0 = sA + w * 512;
  short* dA1 = sA + (w + 4) * 512;
  short* dB0 = sB + w * 512;
  short* dB1 = sB + (w + 4) * 512;

  const int kbeg = blockIdx.z * KSL;
  for (int k0 = kbeg; k0 < kbeg + KSL; k0 += 32) {
    __syncthreads();
    const size_t ko = (size_t)k0 * 16;            // 32 k -> 512 shorts per panel
    gld_lds16(Apan0 + ko, dA0);
    gld_lds16(Apan1 + ko, dA1);
    gld_lds16(Bpan0 + ko, dB0);
    gld_lds16(Bpan1 + ko, dB1);
    __syncthreads();   // drains vmcnt incl. global_load_lds
    bf16x8 af[4], bf[4];
#pragma unroll
    for (int rt = 0; rt < 4; ++rt)
      af[rt] = *(const bf16x8*)(sA + (((wr * 4 + rt) * 64 + quad * 16 + m) << 3));
#pragma unroll
    for (int ct = 0; ct < 4; ++ct)
      bf[ct] = *(const bf16x8*)(sB + (((wc * 4 + ct) * 64 + quad * 16 + m) << 3));
#pragma unroll
    for (int rt = 0; rt < 4; ++rt)
#pragma unroll
      for (int ct = 0; ct < 4; ++ct)
        acc[rt][ct] = __builtin_amdgcn_mfma_f32_16x16x32_bf16(af[rt], bf[ct], acc[rt][ct], 0, 0, 0);
  }

  const int rowbase = bM + wr * 64;
  const int colbase = bN + wc * 64;

  if (MODE == 0) {
    short* dst = (bN < DINNER) ? (short*)out0 : (short*)out1;
    const int cb = (bN < DINNER) ? colbase : colbase - DINNER;
#pragma unroll
    for (int rt = 0; rt < 4; ++rt) {
      const size_t rowPan = ((size_t)((rowbase >> 4) + rt)) << 8;   // *256 chunks
#pragma unroll
      for (int ct = 0; ct < 4; ++ct) {
        const int colA = colbase + ct * 16 + m;      // for bias
        const int colP = cb + ct * 16 + m;           // within 2048-wide target
        const size_t base = ((rowPan + (colP >> 3)) << 7) + (colP & 7) + ((size_t)quad * 32);
#pragma unroll
        for (int reg = 0; reg < 4; ++reg) {
          float val = acc[rt][ct][reg] + bias[colA];
          dst[base + reg * 8] = f2bf(silu_f(val));
        }
      }
    }
  } else {
    short* dst = (short*)out0 + (size_t)blockIdx.z * M * N;
#pragma unroll
    for (int rt = 0; rt < 4; ++rt)
#pragma unroll
      for (int ct = 0; ct < 4; ++ct) {
        const int col = colbase + ct * 16 + m;
#pragma unroll
        for (int reg = 0; reg < 4; ++reg) {
          const int r = rowbase + rt * 16 + quad * 4 + reg;
          dst[(size_t)r * N + col] = f2bf(acc[rt][ct][reg]);
        }
      }
  }
}

// ---------------- split-K combine epilogues ----------------------------------
// G2: p[2][8192][1152] bf16 -> md_sum[r] = sum_c softplus(p0+p1+b_dt), bx
__global__ void g2_epilogue(const short* __restrict__ p, const float* __restrict__ b_dt,
                            const float* __restrict__ b_xp,
                            float* __restrict__ md_sum, float* __restrict__ bx) {
  const int r = blockIdx.x, t = threadIdx.x;
  const size_t base0 = (size_t)r * NCAT;
  const size_t base1 = base0 + (size_t)MROWS * NCAT;
  float s = 0.f;
#pragma unroll
  for (int j = 0; j < 4; ++j) {
    const int c = t + j * 256;
    float v = bf2f(p[base0 + c]) + bf2f(p[base1 + c]) + b_dt[c];
    s += softplus_f(v);
  }
  s += __shfl_xor(s, 1);  s += __shfl_xor(s, 2);  s += __shfl_xor(s, 4);
  s += __shfl_xor(s, 8);  s += __shfl_xor(s, 16); s += __shfl_xor(s, 32);
  __shared__ float wsum[4];
  if ((t & 63) == 0) wsum[t >> 6] = s;
  __syncthreads();
  if (t == 0) md_sum[r] = wsum[0] + wsum[1] + wsum[2] + wsum[3];
  if (t < 64)
    bx[(size_t)r * DSTATE + t] =
        bf2f(p[base0 + 1024 + t]) + bf2f(p[base1 + 1024 + t]) + b_xp[t];
}

// G4: out = p0 + p1 + b_out + x*D   (fp32 row-major [8192,1024])
__global__ void g4_epilogue(const short* __restrict__ p, const float* __restrict__ b_out,
                            const float* __restrict__ x, const float* __restrict__ Dv,
                            float* __restrict__ out) {
  const int r = blockIdx.x, c = threadIdx.x * 4;
  const size_t o = (size_t)r * DMODEL + c;
  short4 a0 = *(const short4*)(p + o);
  short4 a1 = *(const short4*)(p + (size_t)MROWS * DMODEL + o);
  float4 xv = *(const float4*)(x + o);
  float4 ov;
  ov.x = bf2f(a0.x) + bf2f(a1.x) + b_out[c + 0] + xv.x * Dv[c + 0];
  ov.y = bf2f(a0.y) + bf2f(a1.y) + b_out[c + 1] + xv.y * Dv[c + 1];
  ov.z = bf2f(a0.z) + bf2f(a1.z) + b_out[c + 2] + xv.z * Dv[c + 2];
  ov.w = bf2f(a0.w) + bf2f(a1.w) + b_out[c + 3] + xv.w * Dv[c + 3];
  *(float4*)(out + o) = ov;
}

// ---------------- chunked selective scan (3 phases) --------------------------
__global__ void scan_phase1(const float* __restrict__ md_sum, const float* __restrict__ A_log,
                            const float* __restrict__ bx, float* __restrict__ a_buf,
                            float* __restrict__ chunk_prod, float* __restrict__ chunk_end) {
  const int n = threadIdx.x;                // 0..63 (state dim)
  const int c = blockIdx.x & (NCHUNK - 1);  // chunk
  const int b = blockIdx.x >> 6;            // batch
  const float An = -__expf(A_log[n]);
  float prod = 1.f, st = 0.f;
  const int t0 = c * LCHUNK;
  for (int i = 0; i < LCHUNK; ++i) {
    const int t = t0 + i;
    const float md = md_sum[b * SEQ + t] * (1.f / DMODEL);
    const float a = __expf(An * md);
    const size_t idx = ((size_t)(b * SEQ + t)) * DSTATE + n;
    st = a * st + bx[idx];
    prod *= a;
    a_buf[idx] = a;
  }
  chunk_prod[(b * NCHUNK + c) * DSTATE + n] = prod;
  chunk_end [(b * NCHUNK + c) * DSTATE + n] = st;
}

__global__ void scan_phase2(const float* __restrict__ chunk_prod,
                            const float* __restrict__ chunk_end,
                            float* __restrict__ chunk_init) {
  const int i = threadIdx.x;   // 0..127 = b*64 + n
  const int b = i >> 6, n = i & 63;
  float st = 0.f;
  for (int c = 0; c < NCHUNK; ++c) {
    const size_t idx = ((size_t)(b * NCHUNK + c)) * DSTATE + n;
    chunk_init[idx] = st;
    st = chunk_prod[idx] * st + chunk_end[idx];
  }
}

__global__ void scan_phase3(const float* __restrict__ a_buf, const float* __restrict__ bx,
                            const float* __restrict__ chunk_init, float* __restrict__ s_sum) {
  const int n = threadIdx.x;
  const int c = blockIdx.x & (NCHUNK - 1);
  const int b = blockIdx.x >> 6;
  float st = chunk_init[((size_t)(b * NCHUNK + c)) * DSTATE + n];
  const int t0 = c * LCHUNK;
  for (int i = 0; i < LCHUNK; ++i) {
    const int t = t0 + i;
    const size_t idx = ((size_t)(b * SEQ + t)) * DSTATE + n;
    st = a_buf[idx] * st + bx[idx];
    float v = st;
    v += __shfl_xor(v, 32); v += __shfl_xor(v, 16); v += __shfl_xor(v, 8);
    v += __shfl_xor(v, 4);  v += __shfl_xor(v, 2);  v += __shfl_xor(v, 1);
    if (n == 0) s_sum[b * SEQ + t] = v;
  }
}

// ---------------- y = s_sum * xi * g  (panel-staged in AND out, K=2048) ------
__global__ void ymul_kernel(const short* __restrict__ xi, const short* __restrict__ g,
                            const float* __restrict__ s_sum, short* __restrict__ y) {
  const int o = blockIdx.x * 256 + threadIdx.x;    // 16B group index, [0, 2M)
  const int row = ((o >> 12) << 4) | (o & 15);     // panel p = o>>12 (256 chunks)
  const size_t base = (size_t)o * 8;
  const float s = s_sum[row];
  short8 xv = *(const short8*)(xi + base);
  short8 gv = *(const short8*)(g + base);
  short8 yv;
#pragma unroll
  for (int k = 0; k < 8; ++k) yv[k] = f2bf(s * bf2f(xv[k]) * bf2f(gv[k]));
  *(short8*)(y + base) = yv;
}

// ---------------- launch ------------------------------------------------------
extern "C" void kernel_launch(void* const* d_in, const int* in_sizes, int n_in,
                              void* d_out, int out_size, void* d_ws, size_t ws_size,
                              hipStream_t stream) {
  const float* x     = (const float*)d_in[0];
  const float* W_in  = (const float*)d_in[1];
  const float* b_in  = (const float*)d_in[2];
  const float* W_xp  = (const float*)d_in[3];
  const float* b_xp  = (const float*)d_in[4];
  const float* W_dt  = (const float*)d_in[5];
  const float* b_dt  = (const float*)d_in[6];
  const float* W_out = (const float*)d_in[7];
  const float* b_out = (const float*)d_in[8];
  const float* A_log = (const float*)d_in[9];
  const float* Dv    = (const float*)d_in[10];

  char* ws = (char*)d_ws;
  size_t off = 0;
  auto alloc = [&](size_t bytes) -> void* {
    void* p = (void*)(ws + off);
    off += (bytes + 255) & ~(size_t)255;
    return p;
  };
  short* x_bf    = (short*)alloc((size_t)MROWS * DMODEL * 2);
  short* Wt_in   = (short*)alloc((size_t)4096 * 1024 * 2);
  short* Bcat    = (short*)alloc((size_t)NCAT * DINNER * 2);
  short* Wt_out  = (short*)alloc((size_t)1024 * 2048 * 2);
  short* xi      = (short*)alloc((size_t)MROWS * DINNER * 2);   // also G4 partials
  short* gbuf    = (short*)alloc((size_t)MROWS * DINNER * 2);
  short* ybuf    = (short*)alloc((size_t)MROWS * DINNER * 2);
  short* p2      = (short*)alloc((size_t)2 * MROWS * NCAT * 2); // G2 partials
  float* md_sum  = (float*)alloc((size_t)MROWS * 4);
  float* bx      = (float*)alloc((size_t)MROWS * DSTATE * 4);
  float* a_buf   = (float*)alloc((size_t)MROWS * DSTATE * 4);
  float* cprod   = (float*)alloc((size_t)2 * NCHUNK * DSTATE * 4);
  float* cend    = (float*)alloc((size_t)2 * NCHUNK * DSTATE * 4);
  float* cinit   = (float*)alloc((size_t)2 * NCHUNK * DSTATE * 4);
  float* s_sum   = (float*)alloc((size_t)MROWS * 4);

  // fused pre-pass: x->bf16 (panel-staged) + all 4 weight transposes
  prepass_kernel<<<PP4, 256, 0, stream>>>(x, x_bf, W_in, Wt_in, W_dt, W_xp, Bcat, W_out, Wt_out);

  // GEMM1: in_proj + silu split (outputs panel-staged K=2048); full-K
  gemm_bt<0><<<dim3(4096 / 128, MROWS / 128, 1), 256, 0, stream>>>(
      x_bf, Wt_in, b_in, xi, gbuf, MROWS, 4096, 1024, 1024);
  // GEMM2: split-K=2 partials, then epilogue (softplus rowsum + bx)
  gemm_bt<1><<<dim3(NCAT / 128, MROWS / 128, 2), 256, 0, stream>>>(
      xi, Bcat, nullptr, p2, nullptr, MROWS, NCAT, 2048, 1024);
  g2_epilogue<<<MROWS, 256, 0, stream>>>(p2, b_dt, b_xp, md_sum, bx);
  // selective scan
  scan_phase1<<<2 * NCHUNK, DSTATE, 0, stream>>>(md_sum, A_log, bx, a_buf, cprod, cend);
  scan_phase2<<<1, 128, 0, stream>>>(cprod, cend, cinit);
  scan_phase3<<<2 * NCHUNK, DSTATE, 0, stream>>>(a_buf, bx, cinit, s_sum);
  // y = s_sum * xi * g (panel-staged); xi dead afterwards
  ymul_kernel<<<MROWS * DINNER / 8 / 256, 256, 0, stream>>>(xi, gbuf, s_sum, ybuf);
  // GEMM4: split-K=2 partials into xi's slot, then epilogue (+b_out + x*D)
  gemm_bt<1><<<dim3(1024 / 128, MROWS / 128, 2), 256, 0, stream>>>(
      ybuf, Wt_out, nullptr, xi, nullptr, MROWS, 1024, 2048, 1024);
  g4_epilogue<<<MROWS, 256, 0, stream>>>(xi, b_out, x, Dv, (float*)d_out);
}

// Round 6
// 418.334 us; speedup vs baseline: 1.3283x; 1.0420x over previous
//
#include <hip/hip_runtime.h>

#define SEQ 4096
#define DMODEL 1024
#define DSTATE 64
#define DINNER 2048
#define MROWS 8192            // BATCH*SEQ
#define NCAT 1152             // 1024 (dt) + 64 (xp) + 64 pad
#define NCHUNK 64             // scan chunks
#define LCHUNK 64             // steps per chunk

typedef __attribute__((ext_vector_type(8))) __bf16 bf16x8;
typedef __attribute__((ext_vector_type(8))) short short8;
typedef __attribute__((ext_vector_type(4))) float floatx4;

__device__ inline float bf2f(short s) {
  union { unsigned u; float f; } c;
  c.u = ((unsigned)(unsigned short)s) << 16;
  return c.f;
}
__device__ inline short f2bf(float f) {
  union { float f; unsigned u; } c; c.f = f;
  unsigned r = 0x7fffu + ((c.u >> 16) & 1u);
  return (short)((c.u + r) >> 16);
}
__device__ inline float silu_f(float v) {
  return v * __builtin_amdgcn_rcpf(1.f + __expf(-v));
}
__device__ inline float softplus_f(float v) {
  return fmaxf(v, 0.f) + log1pf(__expf(-fabsf(v)));
}
// async global->LDS, 16B per lane. LDS dest = wave-uniform base + lane*16.
__device__ inline void gld_lds16(const void* g, void* l) {
  __builtin_amdgcn_global_load_lds(
      (__attribute__((address_space(1))) void*)g,
      (__attribute__((address_space(3))) void*)l, 16, 0, 0);
}

// panel-staged bf16 layout: panel = 16 rows, stored contiguously (K*32 bytes),
// inside: [k-chunk of 8][row-in-panel 16][8 elems].  element (r,k):
__device__ inline size_t permOff(int r, int k, int K) {
  return (((size_t)(r >> 4) * (K >> 3) + (k >> 3)) << 7) + ((r & 15) << 3) + (k & 7);
}

// ---------------- fused pre-pass ---------------------------------------------
#define PP0 4096
#define PP1 (PP0 + 4096)
#define PP2 (PP1 + 2048)
#define PP3 (PP2 + 128)
#define PP4 (PP3 + 2048)

__device__ void tile_transpose_perm(const float* __restrict__ in, short* __restrict__ out,
                                    int R, int C, int bx, int by, float (*tile)[33]) {
  const int tx = threadIdx.x & 31, ty = threadIdx.x >> 5;   // 32 x 8
  const int cb = bx * 32, rb = by * 32;
#pragma unroll
  for (int i = 0; i < 32; i += 8) {
    int r = rb + ty + i, c = cb + tx;
    tile[ty + i][tx] = (r < R && c < C) ? in[(size_t)r * C + c] : 0.f;
  }
  __syncthreads();
#pragma unroll
  for (int i = 0; i < 32; i += 8) {
    int orow = cb + ty + i, oc = rb + tx;   // out(row=orow, k=oc) = in[oc][orow]
    if (orow < C && oc < R) out[permOff(orow, oc, R)] = f2bf(tile[tx][ty + i]);
  }
}

__global__ void prepass_kernel(const float* __restrict__ x, short* __restrict__ x_bf,
                               const float* __restrict__ W_in, short* __restrict__ Wt_in,
                               const float* __restrict__ W_dt, const float* __restrict__ W_xp,
                               short* __restrict__ Bcat,
                               const float* __restrict__ W_out, short* __restrict__ Wt_out) {
  __shared__ float tile[32][33];
  const int blk = blockIdx.x;
  if (blk < PP0) {
    int o = blk * 256 + threadIdx.x;            // [0, 1M) 16B groups
    int m = o & 15, rest = o >> 4;
    int c = rest & 127, p = rest >> 7;          // K/8 = 128 chunks
    const float* src = x + ((size_t)(p * 16 + m)) * 1024 + c * 8;
    float4 v0 = ((const float4*)src)[0];
    float4 v1 = ((const float4*)src)[1];
    short8 ov;
    ov[0] = f2bf(v0.x); ov[1] = f2bf(v0.y); ov[2] = f2bf(v0.z); ov[3] = f2bf(v0.w);
    ov[4] = f2bf(v1.x); ov[5] = f2bf(v1.y); ov[6] = f2bf(v1.z); ov[7] = f2bf(v1.w);
    ((short8*)x_bf)[o] = ov;
  } else if (blk < PP1) {
    int t = blk - PP0;
    tile_transpose_perm(W_in, Wt_in, 1024, 4096, t & 127, t >> 7, tile);
  } else if (blk < PP2) {
    int t = blk - PP1;
    tile_transpose_perm(W_dt, Bcat, 2048, 1024, t & 31, t >> 5, tile);
  } else if (blk < PP3) {
    int t = blk - PP2;
    tile_transpose_perm(W_xp, Bcat + (size_t)1024 * DINNER, 2048, 64, t & 1, t >> 1, tile);
  } else {
    int t = blk - PP3;
    tile_transpose_perm(W_out, Wt_out, 2048, 1024, t & 31, t >> 5, tile);
  }
}

// ---------------- bf16 GEMM on panel-staged operands -------------------------
// 1D grid with XCD-aware swizzle: xcd = bid&7 owns bM stripe [xcd*8, xcd*8+8),
// so each A-stripe lives in ONE per-XCD L2 (A-tile fetched once, reused by all
// NB column blocks).  Requires M = 8192 (64 bM panels = 8 XCDs x 8).
// MODE 0: full-K; xi=silu (bN<2048) / g=silu (bN>=2048), panel-staged bf16 out
// MODE 1: K-slice z; writes RAW acc as bf16 partial, row-major stride N,
//         at out0 + z*MROWS*N (bias added in the combine epilogue)
template <int MODE, int KTOT, int KSL, int NB, int Z>
__global__ __launch_bounds__(256) void gemm_bt(
    const short* __restrict__ A, const short* __restrict__ Bt,
    const float* __restrict__ bias,
    void* __restrict__ out0, void* __restrict__ out1)
{
  __shared__ __attribute__((aligned(16))) short sA[128 * 32];
  __shared__ __attribute__((aligned(16))) short sB[128 * 32];

  const int tid = threadIdx.x;
  const int lane = tid & 63;
  const int w = tid >> 6;          // wave 0..3
  const int wr = w >> 1, wc = w & 1;
  const int m = lane & 15, quad = lane >> 4;

  // XCD swizzle (compile-time NB/Z -> magic-mul division)
  const int xcd = blockIdx.x & 7;
  const int rest = blockIdx.x >> 3;
  constexpr int PXB = 8 * NB;               // blocks per XCD per z-slice
  const int z = rest / PXB;
  const int q2 = rest - z * PXB;
  const int bM = (xcd * 8 + (q2 & 7)) * 128;
  const int bN = (q2 >> 3) * 128;
  constexpr int N = NB * 128;

  floatx4 acc[4][4] = {};

  const size_t PS = (size_t)KTOT * 16;            // panel stride (shorts)
  const short* Apan0 = A  + ((size_t)(bM >> 4) + w) * PS + lane * 8;
  const short* Apan1 = Apan0 + 4 * PS;
  const short* Bpan0 = Bt + ((size_t)(bN >> 4) + w) * PS + lane * 8;
  const short* Bpan1 = Bpan0 + 4 * PS;
  short* dA0 = sA + w * 512;
  short* dA1 = sA + (w + 4) * 512;
  short* dB0 = sB + w * 512;
  short* dB1 = sB + (w + 4) * 512;

  const int kbeg = z * KSL;
#pragma unroll 2
  for (int k0 = kbeg; k0 < kbeg + KSL; k0 += 32) {
    __syncthreads();
    const size_t ko = (size_t)k0 * 16;            // 32 k -> 512 shorts per panel
    gld_lds16(Apan0 + ko, dA0);
    gld_lds16(Apan1 + ko, dA1);
    gld_lds16(Bpan0 + ko, dB0);
    gld_lds16(Bpan1 + ko, dB1);
    __syncthreads();   // drains vmcnt incl. global_load_lds
    bf16x8 af[4], bf[4];
#pragma unroll
    for (int rt = 0; rt < 4; ++rt)
      af[rt] = *(const bf16x8*)(sA + (((wr * 4 + rt) * 64 + quad * 16 + m) << 3));
#pragma unroll
    for (int ct = 0; ct < 4; ++ct)
      bf[ct] = *(const bf16x8*)(sB + (((wc * 4 + ct) * 64 + quad * 16 + m) << 3));
#pragma unroll
    for (int rt = 0; rt < 4; ++rt)
#pragma unroll
      for (int ct = 0; ct < 4; ++ct)
        acc[rt][ct] = __builtin_amdgcn_mfma_f32_16x16x32_bf16(af[rt], bf[ct], acc[rt][ct], 0, 0, 0);
  }

  const int rowbase = bM + wr * 64;
  const int colbase = bN + wc * 64;

  if (MODE == 0) {
    short* dst = (bN < DINNER) ? (short*)out0 : (short*)out1;
    const int cb = (bN < DINNER) ? colbase : colbase - DINNER;
#pragma unroll
    for (int rt = 0; rt < 4; ++rt) {
      const size_t rowPan = ((size_t)((rowbase >> 4) + rt)) << 8;   // *256 chunks
#pragma unroll
      for (int ct = 0; ct < 4; ++ct) {
        const int colA = colbase + ct * 16 + m;      // for bias
        const int colP = cb + ct * 16 + m;           // within 2048-wide target
        const size_t base = ((rowPan + (colP >> 3)) << 7) + (colP & 7) + ((size_t)quad * 32);
#pragma unroll
        for (int reg = 0; reg < 4; ++reg) {
          float val = acc[rt][ct][reg] + bias[colA];
          dst[base + reg * 8] = f2bf(silu_f(val));
        }
      }
    }
  } else {
    short* dst = (short*)out0 + (size_t)z * MROWS * N;
#pragma unroll
    for (int rt = 0; rt < 4; ++rt)
#pragma unroll
      for (int ct = 0; ct < 4; ++ct) {
        const int col = colbase + ct * 16 + m;
#pragma unroll
        for (int reg = 0; reg < 4; ++reg) {
          const int r = rowbase + rt * 16 + quad * 4 + reg;
          dst[(size_t)r * N + col] = f2bf(acc[rt][ct][reg]);
        }
      }
  }
}

// ---------------- split-K combine epilogues ----------------------------------
// G2: p[2][8192][1152] bf16 -> md_sum[r] = sum_c softplus(p0+p1+b_dt), bx
__global__ void g2_epilogue(const short* __restrict__ p, const float* __restrict__ b_dt,
                            const float* __restrict__ b_xp,
                            float* __restrict__ md_sum, float* __restrict__ bx) {
  const int r = blockIdx.x, t = threadIdx.x;
  const size_t base0 = (size_t)r * NCAT;
  const size_t base1 = base0 + (size_t)MROWS * NCAT;
  float s = 0.f;
#pragma unroll
  for (int j = 0; j < 4; ++j) {
    const int c = t + j * 256;
    float v = bf2f(p[base0 + c]) + bf2f(p[base1 + c]) + b_dt[c];
    s += softplus_f(v);
  }
  s += __shfl_xor(s, 1);  s += __shfl_xor(s, 2);  s += __shfl_xor(s, 4);
  s += __shfl_xor(s, 8);  s += __shfl_xor(s, 16); s += __shfl_xor(s, 32);
  __shared__ float wsum[4];
  if ((t & 63) == 0) wsum[t >> 6] = s;
  __syncthreads();
  if (t == 0) md_sum[r] = wsum[0] + wsum[1] + wsum[2] + wsum[3];
  if (t < 64)
    bx[(size_t)r * DSTATE + t] =
        bf2f(p[base0 + 1024 + t]) + bf2f(p[base1 + 1024 + t]) + b_xp[t];
}

// G4: out = p0 + p1 + b_out + x*D   (fp32 row-major [8192,1024])
__global__ void g4_epilogue(const short* __restrict__ p, const float* __restrict__ b_out,
                            const float* __restrict__ x, const float* __restrict__ Dv,
                            float* __restrict__ out) {
  const int r = blockIdx.x, c = threadIdx.x * 4;
  const size_t o = (size_t)r * DMODEL + c;
  short4 a0 = *(const short4*)(p + o);
  short4 a1 = *(const short4*)(p + (size_t)MROWS * DMODEL + o);
  float4 xv = *(const float4*)(x + o);
  float4 ov;
  ov.x = bf2f(a0.x) + bf2f(a1.x) + b_out[c + 0] + xv.x * Dv[c + 0];
  ov.y = bf2f(a0.y) + bf2f(a1.y) + b_out[c + 1] + xv.y * Dv[c + 1];
  ov.z = bf2f(a0.z) + bf2f(a1.z) + b_out[c + 2] + xv.z * Dv[c + 2];
  ov.w = bf2f(a0.w) + bf2f(a1.w) + b_out[c + 3] + xv.w * Dv[c + 3];
  *(float4*)(out + o) = ov;
}

// ---------------- chunked selective scan (2 phases) --------------------------
__global__ void scan_phase1(const float* __restrict__ md_sum, const float* __restrict__ A_log,
                            const float* __restrict__ bx,
                            float* __restrict__ chunk_prod, float* __restrict__ chunk_end) {
  const int n = threadIdx.x;                // 0..63 (state dim)
  const int c = blockIdx.x & (NCHUNK - 1);  // chunk
  const int b = blockIdx.x >> 6;            // batch
  const float An = -__expf(A_log[n]);
  float prod = 1.f, st = 0.f;
  const int t0 = c * LCHUNK;
  for (int i = 0; i < LCHUNK; ++i) {
    const int t = t0 + i;
    const float md = md_sum[b * SEQ + t] * (1.f / DMODEL);
    const float a = __expf(An * md);
    st = a * st + bx[((size_t)(b * SEQ + t)) * DSTATE + n];
    prod *= a;
  }
  chunk_prod[(b * NCHUNK + c) * DSTATE + n] = prod;
  chunk_end [(b * NCHUNK + c) * DSTATE + n] = st;
}

// phase3 absorbs the old phase2: each block redoes its own chunk-prefix (<=63
// fma steps over 64-wide vectors) and recomputes a=exp(An*md) instead of
// reading a_buf (saves the a_buf round-trip entirely).
__global__ void scan_phase3(const float* __restrict__ md_sum, const float* __restrict__ A_log,
                            const float* __restrict__ bx,
                            const float* __restrict__ chunk_prod,
                            const float* __restrict__ chunk_end,
                            float* __restrict__ s_sum) {
  const int n = threadIdx.x;
  const int c = blockIdx.x & (NCHUNK - 1);
  const int b = blockIdx.x >> 6;
  const float An = -__expf(A_log[n]);
  float st = 0.f;
  for (int cc = 0; cc < c; ++cc) {
    const size_t idx = ((size_t)(b * NCHUNK + cc)) * DSTATE + n;
    st = chunk_prod[idx] * st + chunk_end[idx];
  }
  const int t0 = c * LCHUNK;
  for (int i = 0; i < LCHUNK; ++i) {
    const int t = t0 + i;
    const float md = md_sum[b * SEQ + t] * (1.f / DMODEL);
    const float a = __expf(An * md);
    st = a * st + bx[((size_t)(b * SEQ + t)) * DSTATE + n];
    float v = st;
    v += __shfl_xor(v, 32); v += __shfl_xor(v, 16); v += __shfl_xor(v, 8);
    v += __shfl_xor(v, 4);  v += __shfl_xor(v, 2);  v += __shfl_xor(v, 1);
    if (n == 0) s_sum[b * SEQ + t] = v;
  }
}

// ---------------- y = s_sum * xi * g  (panel-staged in AND out, K=2048) ------
__global__ void ymul_kernel(const short* __restrict__ xi, const short* __restrict__ g,
                            const float* __restrict__ s_sum, short* __restrict__ y) {
  const int o = blockIdx.x * 256 + threadIdx.x;    // 16B group index, [0, 2M)
  const int row = ((o >> 12) << 4) | (o & 15);     // panel p = o>>12 (256 chunks)
  const size_t base = (size_t)o * 8;
  const float s = s_sum[row];
  short8 xv = *(const short8*)(xi + base);
  short8 gv = *(const short8*)(g + base);
  short8 yv;
#pragma unroll
  for (int k = 0; k < 8; ++k) yv[k] = f2bf(s * bf2f(xv[k]) * bf2f(gv[k]));
  *(short8*)(y + base) = yv;
}

// ---------------- launch ------------------------------------------------------
extern "C" void kernel_launch(void* const* d_in, const int* in_sizes, int n_in,
                              void* d_out, int out_size, void* d_ws, size_t ws_size,
                              hipStream_t stream) {
  const float* x     = (const float*)d_in[0];
  const float* W_in  = (const float*)d_in[1];
  const float* b_in  = (const float*)d_in[2];
  const float* W_xp  = (const float*)d_in[3];
  const float* b_xp  = (const float*)d_in[4];
  const float* W_dt  = (const float*)d_in[5];
  const float* b_dt  = (const float*)d_in[6];
  const float* W_out = (const float*)d_in[7];
  const float* b_out = (const float*)d_in[8];
  const float* A_log = (const float*)d_in[9];
  const float* Dv    = (const float*)d_in[10];

  char* ws = (char*)d_ws;
  size_t off = 0;
  auto alloc = [&](size_t bytes) -> void* {
    void* p = (void*)(ws + off);
    off += (bytes + 255) & ~(size_t)255;
    return p;
  };
  short* x_bf    = (short*)alloc((size_t)MROWS * DMODEL * 2);
  short* Wt_in   = (short*)alloc((size_t)4096 * 1024 * 2);
  short* Bcat    = (short*)alloc((size_t)NCAT * DINNER * 2);
  short* Wt_out  = (short*)alloc((size_t)1024 * 2048 * 2);
  short* xi      = (short*)alloc((size_t)MROWS * DINNER * 2);   // also G4 partials
  short* gbuf    = (short*)alloc((size_t)MROWS * DINNER * 2);
  short* ybuf    = (short*)alloc((size_t)MROWS * DINNER * 2);
  short* p2      = (short*)alloc((size_t)2 * MROWS * NCAT * 2); // G2 partials
  float* md_sum  = (float*)alloc((size_t)MROWS * 4);
  float* bx      = (float*)alloc((size_t)MROWS * DSTATE * 4);
  float* cprod   = (float*)alloc((size_t)2 * NCHUNK * DSTATE * 4);
  float* cend    = (float*)alloc((size_t)2 * NCHUNK * DSTATE * 4);
  float* s_sum   = (float*)alloc((size_t)MROWS * 4);

  // fused pre-pass: x->bf16 (panel-staged) + all 4 weight transposes
  prepass_kernel<<<PP4, 256, 0, stream>>>(x, x_bf, W_in, Wt_in, W_dt, W_xp, Bcat, W_out, Wt_out);

  // GEMM1: in_proj + silu split (panel-staged out); XCD-swizzled 1D grid
  gemm_bt<0, 1024, 1024, 32, 1><<<2048, 256, 0, stream>>>(x_bf, Wt_in, b_in, xi, gbuf);
  // GEMM2: split-K=2 partials + epilogue (softplus rowsum + bx)
  gemm_bt<1, 2048, 1024, 9, 2><<<1152, 256, 0, stream>>>(xi, Bcat, nullptr, p2, nullptr);
  g2_epilogue<<<MROWS, 256, 0, stream>>>(p2, b_dt, b_xp, md_sum, bx);
  // selective scan (2 launches; phase3 self-computes its chunk prefix)
  scan_phase1<<<2 * NCHUNK, DSTATE, 0, stream>>>(md_sum, A_log, bx, cprod, cend);
  scan_phase3<<<2 * NCHUNK, DSTATE, 0, stream>>>(md_sum, A_log, bx, cprod, cend, s_sum);
  // y = s_sum * xi * g (panel-staged); xi dead afterwards
  ymul_kernel<<<MROWS * DINNER / 8 / 256, 256, 0, stream>>>(xi, gbuf, s_sum, ybuf);
  // GEMM4: split-K=2 partials into xi's slot + epilogue (+b_out + x*D)
  gemm_bt<1, 2048, 1024, 8, 2><<<1024, 256, 0, stream>>>(ybuf, Wt_out, nullptr, xi, nullptr);
  g4_epilogue<<<MROWS, 256, 0, stream>>>(xi, b_out, x, Dv, (float*)d_out);
}

// Round 7
// 412.388 us; speedup vs baseline: 1.3475x; 1.0144x over previous
//
#include <hip/hip_runtime.h>

#define SEQ 4096
#define DMODEL 1024
#define DSTATE 64
#define DINNER 2048
#define MROWS 8192            // BATCH*SEQ
#define NCAT 1152             // 1024 (dt) + 64 (xp) + 64 pad
#define NCHUNK 64             // scan chunks
#define LCHUNK 64             // steps per chunk

typedef __attribute__((ext_vector_type(8))) __bf16 bf16x8;
typedef __attribute__((ext_vector_type(8))) short short8;
typedef __attribute__((ext_vector_type(4))) float floatx4;

__device__ inline float bf2f(short s) {
  union { unsigned u; float f; } c;
  c.u = ((unsigned)(unsigned short)s) << 16;
  return c.f;
}
__device__ inline short f2bf(float f) {
  union { float f; unsigned u; } c; c.f = f;
  unsigned r = 0x7fffu + ((c.u >> 16) & 1u);
  return (short)((c.u + r) >> 16);
}
__device__ inline float silu_f(float v) {
  return v * __builtin_amdgcn_rcpf(1.f + __expf(-v));
}
__device__ inline float softplus_f(float v) {
  return fmaxf(v, 0.f) + log1pf(__expf(-fabsf(v)));
}
// async global->LDS, 16B per lane. LDS dest = wave-uniform base + lane*16.
__device__ inline void gld_lds16(const void* g, void* l) {
  __builtin_amdgcn_global_load_lds(
      (__attribute__((address_space(1))) void*)g,
      (__attribute__((address_space(3))) void*)l, 16, 0, 0);
}

// panel-staged bf16 layout: panel = 16 rows, stored contiguously (K*32 bytes),
// inside: [k-chunk of 8][row-in-panel 16][8 elems].  element (r,k):
__device__ inline size_t permOff(int r, int k, int K) {
  return (((size_t)(r >> 4) * (K >> 3) + (k >> 3)) << 7) + ((r & 15) << 3) + (k & 7);
}

// ---------------- fused pre-pass ---------------------------------------------
#define PP0 4096
#define PP1 (PP0 + 4096)
#define PP2 (PP1 + 2048)
#define PP3 (PP2 + 128)
#define PP4 (PP3 + 2048)

__device__ void tile_transpose_perm(const float* __restrict__ in, short* __restrict__ out,
                                    int R, int C, int bx, int by, float (*tile)[33]) {
  const int tx = threadIdx.x & 31, ty = threadIdx.x >> 5;   // 32 x 8
  const int cb = bx * 32, rb = by * 32;
#pragma unroll
  for (int i = 0; i < 32; i += 8) {
    int r = rb + ty + i, c = cb + tx;
    tile[ty + i][tx] = (r < R && c < C) ? in[(size_t)r * C + c] : 0.f;
  }
  __syncthreads();
#pragma unroll
  for (int i = 0; i < 32; i += 8) {
    int orow = cb + ty + i, oc = rb + tx;   // out(row=orow, k=oc) = in[oc][orow]
    if (orow < C && oc < R) out[permOff(orow, oc, R)] = f2bf(tile[tx][ty + i]);
  }
}

__global__ void prepass_kernel(const float* __restrict__ x, short* __restrict__ x_bf,
                               const float* __restrict__ W_in, short* __restrict__ Wt_in,
                               const float* __restrict__ W_dt, const float* __restrict__ W_xp,
                               short* __restrict__ Bcat,
                               const float* __restrict__ W_out, short* __restrict__ Wt_out) {
  __shared__ float tile[32][33];
  const int blk = blockIdx.x;
  if (blk < PP0) {
    int o = blk * 256 + threadIdx.x;            // [0, 1M) 16B groups
    int m = o & 15, rest = o >> 4;
    int c = rest & 127, p = rest >> 7;          // K/8 = 128 chunks
    const float* src = x + ((size_t)(p * 16 + m)) * 1024 + c * 8;
    float4 v0 = ((const float4*)src)[0];
    float4 v1 = ((const float4*)src)[1];
    short8 ov;
    ov[0] = f2bf(v0.x); ov[1] = f2bf(v0.y); ov[2] = f2bf(v0.z); ov[3] = f2bf(v0.w);
    ov[4] = f2bf(v1.x); ov[5] = f2bf(v1.y); ov[6] = f2bf(v1.z); ov[7] = f2bf(v1.w);
    ((short8*)x_bf)[o] = ov;
  } else if (blk < PP1) {
    int t = blk - PP0;
    tile_transpose_perm(W_in, Wt_in, 1024, 4096, t & 127, t >> 7, tile);
  } else if (blk < PP2) {
    int t = blk - PP1;
    tile_transpose_perm(W_dt, Bcat, 2048, 1024, t & 31, t >> 5, tile);
  } else if (blk < PP3) {
    int t = blk - PP2;
    tile_transpose_perm(W_xp, Bcat + (size_t)1024 * DINNER, 2048, 64, t & 1, t >> 1, tile);
  } else {
    int t = blk - PP3;
    tile_transpose_perm(W_out, Wt_out, 2048, 1024, t & 31, t >> 5, tile);
  }
}

// ---------------- bf16 GEMM, BK=64 (half the barrier crossings) --------------
// 1D grid, XCD swizzle: xcd=bid&7 owns bM stripe -> A-stripe stays in one L2.
// LDS: panel p (0..7) at [p*1024, p*1024+1024) shorts; chunk cc at cc*128+u*8.
// Frag-read byte addr is exactly lane*16-linear -> conflict-free ds_read_b128.
// MODE 0: full-K; xi=silu (bN<2048) / g=silu (bN>=2048), panel-staged bf16 out
// MODE 1: K-slice z; RAW acc -> bf16 partial, row-major stride N, +z*MROWS*N
template <int MODE, int KTOT, int KSL, int NB, int Z>
__global__ __launch_bounds__(256) void gemm_bt(
    const short* __restrict__ A, const short* __restrict__ Bt,
    const float* __restrict__ bias,
    void* __restrict__ out0, void* __restrict__ out1)
{
  __shared__ __attribute__((aligned(16))) short sA[128 * 64];
  __shared__ __attribute__((aligned(16))) short sB[128 * 64];

  const int tid = threadIdx.x;
  const int lane = tid & 63;
  const int w = tid >> 6;          // wave 0..3
  const int wr = w >> 1, wc = w & 1;
  const int m = lane & 15, quad = lane >> 4;

  const int xcd = blockIdx.x & 7;
  const int rest = blockIdx.x >> 3;
  constexpr int PXB = 8 * NB;               // blocks per XCD per z-slice
  const int z = rest / PXB;
  const int q2 = rest - z * PXB;
  const int bM = (xcd * 8 + (q2 & 7)) * 128;
  const int bN = (q2 >> 3) * 128;
  constexpr int N = NB * 128;

  floatx4 acc[4][4] = {};

  const size_t PS = (size_t)KTOT * 16;            // panel stride (shorts)
  const short* Apan0 = A  + ((size_t)(bM >> 4) + w) * PS + lane * 8;
  const short* Apan1 = Apan0 + 4 * PS;
  const short* Bpan0 = Bt + ((size_t)(bN >> 4) + w) * PS + lane * 8;
  const short* Bpan1 = Bpan0 + 4 * PS;
  short* dA0 = sA + w * 1024;
  short* dA1 = sA + (w + 4) * 1024;
  short* dB0 = sB + w * 1024;
  short* dB1 = sB + (w + 4) * 1024;

  const int kbeg = z * KSL;
  for (int k0 = kbeg; k0 < kbeg + KSL; k0 += 64) {
    __syncthreads();
    const size_t ko = (size_t)k0 * 16;            // 64 k -> 2048 shorts per panel
    gld_lds16(Apan0 + ko,       dA0);
    gld_lds16(Apan0 + ko + 512, dA0 + 512);
    gld_lds16(Apan1 + ko,       dA1);
    gld_lds16(Apan1 + ko + 512, dA1 + 512);
    gld_lds16(Bpan0 + ko,       dB0);
    gld_lds16(Bpan0 + ko + 512, dB0 + 512);
    gld_lds16(Bpan1 + ko,       dB1);
    gld_lds16(Bpan1 + ko + 512, dB1 + 512);
    __syncthreads();   // drains vmcnt incl. global_load_lds
#pragma unroll
    for (int kh = 0; kh < 2; ++kh) {
      bf16x8 af[4], bf[4];
#pragma unroll
      for (int rt = 0; rt < 4; ++rt)
        af[rt] = *(const bf16x8*)(sA + (wr * 4 + rt) * 1024 + (kh * 4 + quad) * 128 + m * 8);
#pragma unroll
      for (int ct = 0; ct < 4; ++ct)
        bf[ct] = *(const bf16x8*)(sB + (wc * 4 + ct) * 1024 + (kh * 4 + quad) * 128 + m * 8);
#pragma unroll
      for (int rt = 0; rt < 4; ++rt)
#pragma unroll
        for (int ct = 0; ct < 4; ++ct)
          acc[rt][ct] = __builtin_amdgcn_mfma_f32_16x16x32_bf16(af[rt], bf[ct], acc[rt][ct], 0, 0, 0);
    }
  }

  const int rowbase = bM + wr * 64;
  const int colbase = bN + wc * 64;

  if (MODE == 0) {
    short* dst = (bN < DINNER) ? (short*)out0 : (short*)out1;
    const int cb = (bN < DINNER) ? colbase : colbase - DINNER;
#pragma unroll
    for (int rt = 0; rt < 4; ++rt) {
      const size_t rowPan = ((size_t)((rowbase >> 4) + rt)) << 8;   // *256 chunks
#pragma unroll
      for (int ct = 0; ct < 4; ++ct) {
        const int colA = colbase + ct * 16 + m;      // for bias
        const int colP = cb + ct * 16 + m;           // within 2048-wide target
        const size_t base = ((rowPan + (colP >> 3)) << 7) + (colP & 7) + ((size_t)quad * 32);
#pragma unroll
        for (int reg = 0; reg < 4; ++reg) {
          float val = acc[rt][ct][reg] + bias[colA];
          dst[base + reg * 8] = f2bf(silu_f(val));
        }
      }
    }
  } else {
    if (NB == 9 && colbase >= 1088) return;          // pad columns: drop
    short* dst = (short*)out0 + (size_t)z * MROWS * N;
#pragma unroll
    for (int rt = 0; rt < 4; ++rt)
#pragma unroll
      for (int ct = 0; ct < 4; ++ct) {
        const int col = colbase + ct * 16 + m;
#pragma unroll
        for (int reg = 0; reg < 4; ++reg) {
          const int r = rowbase + rt * 16 + quad * 4 + reg;
          dst[(size_t)r * N + col] = f2bf(acc[rt][ct][reg]);
        }
      }
  }
}

// ---------------- split-K combine epilogues ----------------------------------
// G2: one wave per row; p[2][8192][1152] bf16 -> md_sum, bx
__global__ void g2_epilogue(const short* __restrict__ p, const float* __restrict__ b_dt,
                            const float* __restrict__ b_xp,
                            float* __restrict__ md_sum, float* __restrict__ bx) {
  const int row = blockIdx.x * 4 + (threadIdx.x >> 6);
  const int lane = threadIdx.x & 63;
  const size_t base0 = (size_t)row * NCAT;
  const size_t base1 = base0 + (size_t)MROWS * NCAT;
  short8 a0 = *(const short8*)(p + base0 + lane * 16);
  short8 a1 = *(const short8*)(p + base0 + lane * 16 + 8);
  short8 c0 = *(const short8*)(p + base1 + lane * 16);
  short8 c1 = *(const short8*)(p + base1 + lane * 16 + 8);
  float s = 0.f;
#pragma unroll
  for (int j = 0; j < 8; ++j) {
    s += softplus_f(bf2f(a0[j]) + bf2f(c0[j]) + b_dt[lane * 16 + j]);
    s += softplus_f(bf2f(a1[j]) + bf2f(c1[j]) + b_dt[lane * 16 + 8 + j]);
  }
  s += __shfl_xor(s, 1);  s += __shfl_xor(s, 2);  s += __shfl_xor(s, 4);
  s += __shfl_xor(s, 8);  s += __shfl_xor(s, 16); s += __shfl_xor(s, 32);
  if (lane == 0) md_sum[row] = s;
  bx[(size_t)row * DSTATE + lane] =
      bf2f(p[base0 + 1024 + lane]) + bf2f(p[base1 + 1024 + lane]) + b_xp[lane];
}

// G4: out = p0 + p1 + b_out + x*D   (fp32 row-major [8192,1024])
__global__ void g4_epilogue(const short* __restrict__ p, const float* __restrict__ b_out,
                            const float* __restrict__ x, const float* __restrict__ Dv,
                            float* __restrict__ out) {
  const int r = blockIdx.x, c = threadIdx.x * 4;
  const size_t o = (size_t)r * DMODEL + c;
  short4 a0 = *(const short4*)(p + o);
  short4 a1 = *(const short4*)(p + (size_t)MROWS * DMODEL + o);
  float4 xv = *(const float4*)(x + o);
  float4 ov;
  ov.x = bf2f(a0.x) + bf2f(a1.x) + b_out[c + 0] + xv.x * Dv[c + 0];
  ov.y = bf2f(a0.y) + bf2f(a1.y) + b_out[c + 1] + xv.y * Dv[c + 1];
  ov.z = bf2f(a0.z) + bf2f(a1.z) + b_out[c + 2] + xv.z * Dv[c + 2];
  ov.w = bf2f(a0.w) + bf2f(a1.w) + b_out[c + 3] + xv.w * Dv[c + 3];
  *(float4*)(out + o) = ov;
}

// ---------------- chunked selective scan (2 phases) --------------------------
__global__ void scan_phase1(const float* __restrict__ md_sum, const float* __restrict__ A_log,
                            const float* __restrict__ bx,
                            float* __restrict__ chunk_prod, float* __restrict__ chunk_end) {
  const int n = threadIdx.x;                // 0..63 (state dim)
  const int c = blockIdx.x & (NCHUNK - 1);  // chunk
  const int b = blockIdx.x >> 6;            // batch
  const float An = -__expf(A_log[n]);
  float prod = 1.f, st = 0.f;
  const int t0 = c * LCHUNK;
#pragma unroll 4
  for (int i = 0; i < LCHUNK; ++i) {
    const int t = t0 + i;
    const float md = md_sum[b * SEQ + t] * (1.f / DMODEL);
    const float a = __expf(An * md);
    st = a * st + bx[((size_t)(b * SEQ + t)) * DSTATE + n];
    prod *= a;
  }
  chunk_prod[(b * NCHUNK + c) * DSTATE + n] = prod;
  chunk_end [(b * NCHUNK + c) * DSTATE + n] = st;
}

// phase3: redo own chunk-prefix, recompute a=exp(An*md), emit s_sum
__global__ void scan_phase3(const float* __restrict__ md_sum, const float* __restrict__ A_log,
                            const float* __restrict__ bx,
                            const float* __restrict__ chunk_prod,
                            const float* __restrict__ chunk_end,
                            float* __restrict__ s_sum) {
  const int n = threadIdx.x;
  const int c = blockIdx.x & (NCHUNK - 1);
  const int b = blockIdx.x >> 6;
  const float An = -__expf(A_log[n]);
  float st = 0.f;
  for (int cc = 0; cc < c; ++cc) {
    const size_t idx = ((size_t)(b * NCHUNK + cc)) * DSTATE + n;
    st = chunk_prod[idx] * st + chunk_end[idx];
  }
  const int t0 = c * LCHUNK;
#pragma unroll 4
  for (int i = 0; i < LCHUNK; ++i) {
    const int t = t0 + i;
    const float md = md_sum[b * SEQ + t] * (1.f / DMODEL);
    const float a = __expf(An * md);
    st = a * st + bx[((size_t)(b * SEQ + t)) * DSTATE + n];
    float v = st;
    v += __shfl_xor(v, 32); v += __shfl_xor(v, 16); v += __shfl_xor(v, 8);
    v += __shfl_xor(v, 4);  v += __shfl_xor(v, 2);  v += __shfl_xor(v, 1);
    if (n == 0) s_sum[b * SEQ + t] = v;
  }
}

// ---------------- y = s_sum * xi * g  (panel-staged in AND out, K=2048) ------
__global__ void ymul_kernel(const short* __restrict__ xi, const short* __restrict__ g,
                            const float* __restrict__ s_sum, short* __restrict__ y) {
  const int o = blockIdx.x * 256 + threadIdx.x;    // 16B group index, [0, 2M)
  const int row = ((o >> 12) << 4) | (o & 15);     // panel p = o>>12 (256 chunks)
  const size_t base = (size_t)o * 8;
  const float s = s_sum[row];
  short8 xv = *(const short8*)(xi + base);
  short8 gv = *(const short8*)(g + base);
  short8 yv;
#pragma unroll
  for (int k = 0; k < 8; ++k) yv[k] = f2bf(s * bf2f(xv[k]) * bf2f(gv[k]));
  *(short8*)(y + base) = yv;
}

// ---------------- launch ------------------------------------------------------
extern "C" void kernel_launch(void* const* d_in, const int* in_sizes, int n_in,
                              void* d_out, int out_size, void* d_ws, size_t ws_size,
                              hipStream_t stream) {
  const float* x     = (const float*)d_in[0];
  const float* W_in  = (const float*)d_in[1];
  const float* b_in  = (const float*)d_in[2];
  const float* W_xp  = (const float*)d_in[3];
  const float* b_xp  = (const float*)d_in[4];
  const float* W_dt  = (const float*)d_in[5];
  const float* b_dt  = (const float*)d_in[6];
  const float* W_out = (const float*)d_in[7];
  const float* b_out = (const float*)d_in[8];
  const float* A_log = (const float*)d_in[9];
  const float* Dv    = (const float*)d_in[10];

  char* ws = (char*)d_ws;
  size_t off = 0;
  auto alloc = [&](size_t bytes) -> void* {
    void* p = (void*)(ws + off);
    off += (bytes + 255) & ~(size_t)255;
    return p;
  };
  short* x_bf    = (short*)alloc((size_t)MROWS * DMODEL * 2);
  short* Wt_in   = (short*)alloc((size_t)4096 * 1024 * 2);
  short* Bcat    = (short*)alloc((size_t)NCAT * DINNER * 2);
  short* Wt_out  = (short*)alloc((size_t)1024 * 2048 * 2);
  short* xi      = (short*)alloc((size_t)MROWS * DINNER * 2);   // also G4 partials
  short* gbuf    = (short*)alloc((size_t)MROWS * DINNER * 2);
  short* ybuf    = (short*)alloc((size_t)MROWS * DINNER * 2);
  short* p2      = (short*)alloc((size_t)2 * MROWS * NCAT * 2); // G2 partials
  float* md_sum  = (float*)alloc((size_t)MROWS * 4);
  float* bx      = (float*)alloc((size_t)MROWS * DSTATE * 4);
  float* cprod   = (float*)alloc((size_t)2 * NCHUNK * DSTATE * 4);
  float* cend    = (float*)alloc((size_t)2 * NCHUNK * DSTATE * 4);
  float* s_sum   = (float*)alloc((size_t)MROWS * 4);

  // fused pre-pass: x->bf16 (panel-staged) + all 4 weight transposes
  prepass_kernel<<<PP4, 256, 0, stream>>>(x, x_bf, W_in, Wt_in, W_dt, W_xp, Bcat, W_out, Wt_out);

  // GEMM1: in_proj + silu split (panel-staged out); XCD-swizzled 1D grid
  gemm_bt<0, 1024, 1024, 32, 1><<<2048, 256, 0, stream>>>(x_bf, Wt_in, b_in, xi, gbuf);
  // GEMM2: split-K=2 partials + epilogue (softplus rowsum + bx)
  gemm_bt<1, 2048, 1024, 9, 2><<<1152, 256, 0, stream>>>(xi, Bcat, nullptr, p2, nullptr);
  g2_epilogue<<<MROWS / 4, 256, 0, stream>>>(p2, b_dt, b_xp, md_sum, bx);
  // selective scan (phase3 self-computes its chunk prefix)
  scan_phase1<<<2 * NCHUNK, DSTATE, 0, stream>>>(md_sum, A_log, bx, cprod, cend);
  scan_phase3<<<2 * NCHUNK, DSTATE, 0, stream>>>(md_sum, A_log, bx, cprod, cend, s_sum);
  // y = s_sum * xi * g (panel-staged); xi dead afterwards
  ymul_kernel<<<MROWS * DINNER / 8 / 256, 256, 0, stream>>>(xi, gbuf, s_sum, ybuf);
  // GEMM4: split-K=2 partials into xi's slot + epilogue (+b_out + x*D)
  gemm_bt<1, 2048, 1024, 8, 2><<<1024, 256, 0, stream>>>(ybuf, Wt_out, nullptr, xi, nullptr);
  g4_epilogue<<<MROWS, 256, 0, stream>>>(xi, b_out, x, Dv, (float*)d_out);
}